// Round 1
// baseline (321.813 us; speedup 1.0000x reference)
//
#include <hip/hip_runtime.h>

#define BLOCK 256
#define GRID  2048
#define NTOTAL 33554432  // 2^25

__device__ __forceinline__ float wave_reduce(float v) {
  #pragma unroll
  for (int off = 32; off > 0; off >>= 1)
    v += __shfl_down(v, off, 64);
  return v;
}

__device__ __forceinline__ void block_atomic_add(float v, double* target) {
  __shared__ float smem[BLOCK / 64];
  float wv = wave_reduce(v);
  const int lane = threadIdx.x & 63;
  const int wid  = threadIdx.x >> 6;
  if (lane == 0) smem[wid] = wv;
  __syncthreads();
  if (threadIdx.x == 0) {
    float tot = 0.f;
    #pragma unroll
    for (int i = 0; i < BLOCK / 64; ++i) tot += smem[i];
    atomicAdd(target, (double)tot);  // device-scope f64 atomic on gfx950
  }
}

__global__ void __launch_bounds__(BLOCK) sum_kernel(const float4* __restrict__ in,
                                                    double* __restrict__ ws) {
  const int n4 = NTOTAL / 4;
  float acc = 0.f;
  for (int i = blockIdx.x * BLOCK + threadIdx.x; i < n4; i += GRID * BLOCK) {
    float4 v = in[i];
    acc += (v.x + v.y) + (v.z + v.w);
  }
  block_atomic_add(acc, &ws[0]);
}

// W0(x) on x in (-1/e, ~0.5): series/small-x initial guess + 3 Halley iters.
// (x > e branch of the reference is unreachable here: x = 0.5*(loss - tau) < 0.5.)
__device__ __forceinline__ float lambertw0f(float x) {
  const float E1 = 2.718281828459045f;
  float p = sqrtf(fmaxf(2.0f * fmaf(E1, x, 1.0f), 0.0f));
  float w_near  = p - 1.0f;          // branch-point series: W ~ -1 + sqrt(2(1+e x))
  float w_small = x * (1.0f - x);    // W ~ x - x^2
  float w = (x < -0.25f) ? w_near : w_small;
  #pragma unroll
  for (int i = 0; i < 3; ++i) {
    float ew   = __expf(w);
    float f    = fmaf(w, ew, -x);
    float wp1  = w + 1.0f;
    float denom = fmaf(ew, wp1, -(w + 2.0f) * f / (2.0f * wp1));
    w -= f / denom;
  }
  return w;
}

__global__ void __launch_bounds__(BLOCK) superloss_kernel(const float4* __restrict__ in,
                                                          const double* __restrict__ ws_in,
                                                          double* __restrict__ ws_out) {
  const int n4 = NTOTAL / 4;
  const float tau = (float)(ws_in[0] * (1.0 / (double)NTOTAL));
  const float gamma = (float)(-2.0 / 2.718281828459045235360287 + 1e-12);
  float acc = 0.f;
  for (int i = blockIdx.x * BLOCK + threadIdx.x; i < n4; i += GRID * BLOCK) {
    float4 v = in[i];
    float vals[4] = {v.x, v.y, v.z, v.w};
    #pragma unroll
    for (int j = 0; j < 4; ++j) {
      float beta  = vals[j] - tau;
      float x     = 0.5f * fmaxf(beta, gamma);
      float w     = lambertw0f(x);
      float sigma = __expf(-w);
      acc += fmaf(beta, sigma, w * w);  // (loss - tau)*sigma + log(sigma)^2
    }
  }
  block_atomic_add(acc, ws_out);
}

__global__ void finalize_kernel(const double* __restrict__ ws, float* __restrict__ out) {
  out[0] = (float)(ws[1] * (1.0 / (double)NTOTAL));
}

extern "C" void kernel_launch(void* const* d_in, const int* in_sizes, int n_in,
                              void* d_out, int out_size, void* d_ws, size_t ws_size,
                              hipStream_t stream) {
  const float4* loss4 = (const float4*)d_in[0];
  double* ws = (double*)d_ws;
  // d_ws is poisoned to 0xAA before every launch — zero the two accumulators.
  hipMemsetAsync(ws, 0, 2 * sizeof(double), stream);
  sum_kernel<<<GRID, BLOCK, 0, stream>>>(loss4, ws);
  superloss_kernel<<<GRID, BLOCK, 0, stream>>>(loss4, ws, ws + 1);
  finalize_kernel<<<1, 1, 0, stream>>>(ws, (float*)d_out);
}